// Round 5
// baseline (3804.140 us; speedup 1.0000x reference)
//
#include <hip/hip_runtime.h>
#include <math.h>

typedef _Float16 f16;
typedef _Float16 f16x8 __attribute__((ext_vector_type(8)));
typedef float    f32x4 __attribute__((ext_vector_type(4)));

#define BATCH 256
#define SEQ   1024
#define DI    128
#define DH    128
#define DM    144
#define NTH   256
#define MR    16
#define SXS   136   // f16 stride, 128-col activation panels (odd*8 -> conflict-free frags)
#define SYS   168   // f16 stride, 160-col (144+pad) panels
#define SZS   132   // f32 stride

#define MFMA16(a, b, c) __builtin_amdgcn_mfma_f32_16x16x32_f16((a), (b), (c), 0, 0, 0)

__device__ __forceinline__ float sigm(float x) { return 1.f / (1.f + __expf(-x)); }
__device__ __forceinline__ float tanh_fast(float x) {
    const float e = __expf(2.f * x);
    return 1.f - 2.f / (e + 1.f);
}

// Barrier that waits only on LDS ops: global loads/stores stay in flight (T4).
// Cross-wave LDS visibility needs lgkmcnt(0) + s_barrier only; the compiler
// still inserts value-dep vmcnt(N) waits before prefetched registers are used.
__device__ __forceinline__ void bar_lds() {
    asm volatile("s_waitcnt lgkmcnt(0)" ::: "memory");
    __builtin_amdgcn_s_barrier();
}

__global__ __launch_bounds__(NTH, 1) void hgru_kernel(
    const float* __restrict__ inputs,
    const float* __restrict__ r_w, const float* __restrict__ r_b,
    const float* __restrict__ z_w, const float* __restrict__ z_b,
    const float* __restrict__ h_w0, const float* __restrict__ h_b0,
    const float* __restrict__ h_w1, const float* __restrict__ h_b1,
    const float* __restrict__ h_w2, const float* __restrict__ h_b2,
    float* __restrict__ out, float* __restrict__ hid_out)
{
    __shared__ __align__(16) f16   sx [MR * SXS];   // x_{t+1} staging (single buffer)
    __shared__ __align__(16) f16   sh16[MR * SXS];  // h as f16 A-panel
    __shared__ __align__(16) f16   srh[MR * SXS];   // r*h A-panel
    __shared__ __align__(16) f16   sy0[MR * SYS];   // mlp act1 (zero-padded to 160)
    __shared__ __align__(16) f16   sy1[MR * SYS];   // mlp act2
    __shared__ __align__(16) float sz [MR * SZS];   // z gate f32
    __shared__ __align__(16) float shf[MR * SZS];   // master h state f32

    const int tid  = threadIdx.x;
    const int w    = tid >> 6;      // wave 0..3
    const int lane = tid & 63;
    const int ln   = lane & 15;     // A-row / B-col / C-col
    const int kg   = lane >> 4;     // k-group; C-row base = 4*kg
    const int b0   = blockIdx.x * MR;

    // stage-2/3 N-tile distribution over 9 tiles: s2 = [3,2,2,2], s3 = [2,3,2,2]
    const int nt2    = (w == 0) ? 3 : 2;
    const int t2base = (w == 0) ? 0 : 1 + 2 * w;          // w1:3 w2:5 w3:7
    const int nt3    = (w == 1) ? 3 : 2;
    const int t3base = (w == 0) ? 0 : (w == 1) ? 2 : 1 + 2 * w;  // w2:5 w3:7

    // ---------------- zero-init LDS ----------------
    for (int i = tid; i < MR * SYS; i += NTH) { sy0[i] = (f16)0.f; sy1[i] = (f16)0.f; }
    for (int i = tid; i < MR * SXS; i += NTH) { sh16[i] = (f16)0.f; }
    for (int i = tid; i < MR * SZS; i += NTH) { shf[i] = 0.f; }

    // ---------------- register weight fragments ----------------
    // B-frag convention (round-3 verified): elem j = W[kt*32 + kg*8 + j][col + ln]
    const bool is_r = (w < 2);
    const float* __restrict__ Wg = is_r ? r_w : z_w;

    f16x8 wgx[4][4], wgh[4][4];   // gates: 4 N-tiles/wave; x-rows / h-rows
    #pragma unroll
    for (int nt = 0; nt < 4; ++nt) {
        const int col = ((4 * w + nt) & 7) * 16 + ln;
        #pragma unroll
        for (int kt = 0; kt < 4; ++kt) {
            f16x8 fx, fh;
            #pragma unroll
            for (int j = 0; j < 8; ++j) {
                const int k = kt * 32 + kg * 8 + j;
                fx[j] = (f16)Wg[(size_t)k * DH + col];
                fh[j] = (f16)Wg[(size_t)(DI + k) * DH + col];
            }
            wgx[nt][kt] = fx; wgh[nt][kt] = fh;
        }
    }

    f16x8 w0x[3][4], w0h[3][4];   // h_w0: x-rows / rh-rows, per-wave s2 tiles
    #pragma unroll
    for (int i = 0; i < 3; ++i) if (i < nt2) {
        const int col = (t2base + i) * 16 + ln;
        #pragma unroll
        for (int kt = 0; kt < 4; ++kt) {
            f16x8 fx, fh;
            #pragma unroll
            for (int j = 0; j < 8; ++j) {
                const int k = kt * 32 + kg * 8 + j;
                fx[j] = (f16)h_w0[(size_t)k * DM + col];
                fh[j] = (f16)h_w0[(size_t)(DI + k) * DM + col];
            }
            w0x[i][kt] = fx; w0h[i][kt] = fh;
        }
    }

    f16x8 w1f[3][5];              // h_w1, K padded 144->160
    #pragma unroll
    for (int i = 0; i < 3; ++i) if (i < nt3) {
        const int col = (t3base + i) * 16 + ln;
        #pragma unroll
        for (int kt = 0; kt < 5; ++kt) {
            f16x8 f;
            #pragma unroll
            for (int j = 0; j < 8; ++j) {
                const int k = kt * 32 + kg * 8 + j;
                f[j] = (k < DM) ? (f16)h_w1[(size_t)k * DM + col] : (f16)0.f;
            }
            w1f[i][kt] = f;
        }
    }

    f16x8 w2f[2][5];              // h_w2
    #pragma unroll
    for (int i = 0; i < 2; ++i) {
        const int col = (2 * w + i) * 16 + ln;
        #pragma unroll
        for (int kt = 0; kt < 5; ++kt) {
            f16x8 f;
            #pragma unroll
            for (int j = 0; j < 8; ++j) {
                const int k = kt * 32 + kg * 8 + j;
                f[j] = (k < DM) ? (f16)h_w2[(size_t)k * DH + col] : (f16)0.f;
            }
            w2f[i][kt] = f;
        }
    }

    // biases
    float b1[4], b2[3], b3[3], b4[2];
    #pragma unroll
    for (int nt = 0; nt < 4; ++nt)
        b1[nt] = (is_r ? r_b : z_b)[((4 * w + nt) & 7) * 16 + ln];
    #pragma unroll
    for (int i = 0; i < 3; ++i) { b2[i] = 0.f; b3[i] = 0.f; }
    #pragma unroll
    for (int i = 0; i < 3; ++i) if (i < nt2) b2[i] = h_b0[(t2base + i) * 16 + ln];
    #pragma unroll
    for (int i = 0; i < 3; ++i) if (i < nt3) b3[i] = h_b1[(t3base + i) * 16 + ln];
    #pragma unroll
    for (int i = 0; i < 2; ++i) b4[i] = h_b2[(2 * w + i) * 16 + ln];

    // ---------------- x staging: thread -> (row = tid>>4, 8 f16 at seg = tid&15) ----------------
    const int xrow = tid >> 4;
    const int xseg = tid & 15;
    const float* __restrict__ xbase = inputs + (size_t)(b0 + xrow) * SEQ * DI + xseg * 8;

    {   // publish x(0)
        const float4 a = ((const float4*)xbase)[0];
        const float4 b = ((const float4*)(xbase + 4))[0];
        f16x8 v; v[0]=(f16)a.x; v[1]=(f16)a.y; v[2]=(f16)a.z; v[3]=(f16)a.w;
                 v[4]=(f16)b.x; v[5]=(f16)b.y; v[6]=(f16)b.z; v[7]=(f16)b.w;
        *(f16x8*)(sx + xrow * SXS + xseg * 8) = v;
    }
    // prefetch x(1)
    float4 xpA0 = ((const float4*)(xbase + (size_t)1 * DI))[0];
    float4 xpA1 = ((const float4*)(xbase + (size_t)1 * DI + 4))[0];

    bar_lds();

    const f32x4 z4 = {0.f, 0.f, 0.f, 0.f};
    f32x4 PG[4], PM[3];

    // ---- init PG/PM with x(0) contributions ----
    {
        f16x8 xa[4];
        #pragma unroll
        for (int kt = 0; kt < 4; ++kt)
            xa[kt] = *(const f16x8*)(sx + ln * SXS + kt * 32 + kg * 8);
        #pragma unroll
        for (int nt = 0; nt < 4; ++nt) {
            f32x4 a = z4;
            #pragma unroll
            for (int kt = 0; kt < 4; ++kt) a = MFMA16(xa[kt], wgx[nt][kt], a);
            PG[nt] = a;
        }
        #pragma unroll
        for (int i = 0; i < 3; ++i) { PM[i] = z4; }
        #pragma unroll
        for (int i = 0; i < 3; ++i) if (i < nt2) {
            f32x4 a = z4;
            #pragma unroll
            for (int kt = 0; kt < 4; ++kt) a = MFMA16(xa[kt], w0x[i][kt], a);
            PM[i] = a;
        }
    }

    for (int t = 0; t < SEQ; ++t) {
        // prefetch x(t+2) (stays in flight; value-dep vmcnt wait lands next step)
        const int tn = (t + 2 < SEQ) ? t + 2 : SEQ - 1;
        const float4 xpB0 = ((const float4*)(xbase + (size_t)tn * DI))[0];
        const float4 xpB1 = ((const float4*)(xbase + (size_t)tn * DI + 4))[0];

        // ======== stage 1: gates — h-part into PG (x-part already there) ========
        {
            f16x8 ha[4];
            #pragma unroll
            for (int kt = 0; kt < 4; ++kt)
                ha[kt] = *(const f16x8*)(sh16 + ln * SXS + kt * 32 + kg * 8);
            #pragma unroll
            for (int nt = 0; nt < 4; ++nt) {
                f32x4 a = PG[nt];
                #pragma unroll
                for (int kt = 0; kt < 4; ++kt) a = MFMA16(ha[kt], wgh[nt][kt], a);
                PG[nt] = a;
            }
        }
        // epilogue: sigmoid; r-waves write r*h, z-waves write z
        #pragma unroll
        for (int nt = 0; nt < 4; ++nt) {
            const int n = ((4 * w + nt) & 7) * 16 + ln;
            #pragma unroll
            for (int j = 0; j < 4; ++j) {
                const int m = 4 * kg + j;
                const float g = sigm(PG[nt][j] + b1[nt]);
                if (is_r) srh[m * SXS + n] = (f16)(g * shf[m * SZS + n]);
                else      sz[m * SZS + n] = g;
            }
        }
        bar_lds(); // A

        // ======== stage 2: y0 = relu(x-part(PM) + rh @ w0h + b) ========
        {
            f16x8 ra[4];
            #pragma unroll
            for (int kt = 0; kt < 4; ++kt)
                ra[kt] = *(const f16x8*)(srh + ln * SXS + kt * 32 + kg * 8);
            #pragma unroll
            for (int i = 0; i < 3; ++i) if (i < nt2) {
                f32x4 a = PM[i];
                #pragma unroll
                for (int kt = 0; kt < 4; ++kt) a = MFMA16(ra[kt], w0h[i][kt], a);
                PM[i] = a;
            }
        }
        #pragma unroll
        for (int i = 0; i < 3; ++i) if (i < nt2) {
            const int n = (t2base + i) * 16 + ln;
            #pragma unroll
            for (int j = 0; j < 4; ++j)
                sy0[(4 * kg + j) * SYS + n] = (f16)fmaxf(PM[i][j] + b2[i], 0.f);
        }
        // publish x(t+1) (readers of x(t) finished last step)
        {
            f16x8 v; v[0]=(f16)xpA0.x; v[1]=(f16)xpA0.y; v[2]=(f16)xpA0.z; v[3]=(f16)xpA0.w;
                     v[4]=(f16)xpA1.x; v[5]=(f16)xpA1.y; v[6]=(f16)xpA1.z; v[7]=(f16)xpA1.w;
            *(f16x8*)(sx + xrow * SXS + xseg * 8) = v;
        }
        bar_lds(); // B

        // ======== stage 3: y1 = relu(y0 @ h_w1 + b) ========
        {
            f16x8 ya[5];
            #pragma unroll
            for (int kt = 0; kt < 5; ++kt)
                ya[kt] = *(const f16x8*)(sy0 + ln * SYS + kt * 32 + kg * 8);
            #pragma unroll
            for (int i = 0; i < 3; ++i) if (i < nt3) {
                f32x4 a = z4;
                #pragma unroll
                for (int kt = 0; kt < 5; ++kt) a = MFMA16(ya[kt], w1f[i][kt], a);
                const int n = (t3base + i) * 16 + ln;
                #pragma unroll
                for (int j = 0; j < 4; ++j)
                    sy1[(4 * kg + j) * SYS + n] = (f16)fmaxf(a[j] + b3[i], 0.f);
            }
        }
        bar_lds(); // C

        // ======== stage 4: h~ = tanh(y1 @ h_w2 + b2); h update ========
        // plus overlap: next step's x-projections into PG/PM (off critical path)
        f32x4 r4[2];
        {
            f16x8 za[5];
            #pragma unroll
            for (int kt = 0; kt < 5; ++kt)
                za[kt] = *(const f16x8*)(sy1 + ln * SYS + kt * 32 + kg * 8);
            #pragma unroll
            for (int i = 0; i < 2; ++i) {
                f32x4 a = z4;
                #pragma unroll
                for (int kt = 0; kt < 5; ++kt) a = MFMA16(za[kt], w2f[i][kt], a);
                r4[i] = a;
            }
        }
        {
            f16x8 xa[4];
            #pragma unroll
            for (int kt = 0; kt < 4; ++kt)
                xa[kt] = *(const f16x8*)(sx + ln * SXS + kt * 32 + kg * 8);
            #pragma unroll
            for (int nt = 0; nt < 4; ++nt) {
                f32x4 a = z4;
                #pragma unroll
                for (int kt = 0; kt < 4; ++kt) a = MFMA16(xa[kt], wgx[nt][kt], a);
                PG[nt] = a;
            }
            #pragma unroll
            for (int i = 0; i < 3; ++i) if (i < nt2) {
                f32x4 a = z4;
                #pragma unroll
                for (int kt = 0; kt < 4; ++kt) a = MFMA16(xa[kt], w0x[i][kt], a);
                PM[i] = a;
            }
        }
        #pragma unroll
        for (int i = 0; i < 2; ++i) {
            const int n = (2 * w + i) * 16 + ln;
            #pragma unroll
            for (int j = 0; j < 4; ++j) {
                const int m = 4 * kg + j;
                const float ht = tanh_fast(r4[i][j] + b4[i]);
                const float zz = sz[m * SZS + n];
                const float hn = (1.f - zz) * shf[m * SZS + n] + zz * ht;
                shf[m * SZS + n] = hn;
                sh16[m * SXS + n] = (f16)hn;
                // store immediately: stays in VMEM queue, no barrier drains it
                out[((size_t)(b0 + m) * SEQ + t) * DH + n] = hn;
            }
        }
        bar_lds(); // D

        xpA0 = xpB0; xpA1 = xpB1;
    }

    for (int i = tid; i < MR * DH; i += NTH)
        hid_out[(size_t)(b0 + (i >> 7)) * DH + (i & 127)] = shf[(i >> 7) * SZS + (i & 127)];
}

extern "C" void kernel_launch(void* const* d_in, const int* in_sizes, int n_in,
                              void* d_out, int out_size, void* d_ws, size_t ws_size,
                              hipStream_t stream) {
    const float* inputs = (const float*)d_in[0];
    const float* r_w  = (const float*)d_in[1];
    const float* r_b  = (const float*)d_in[2];
    const float* z_w  = (const float*)d_in[3];
    const float* z_b  = (const float*)d_in[4];
    const float* h_w0 = (const float*)d_in[5];
    const float* h_b0 = (const float*)d_in[6];
    const float* h_w1 = (const float*)d_in[7];
    const float* h_b1 = (const float*)d_in[8];
    const float* h_w2 = (const float*)d_in[9];
    const float* h_b2 = (const float*)d_in[10];

    float* out = (float*)d_out;
    float* hid = out + (size_t)BATCH * SEQ * DH;

    hipLaunchKernelGGL(hgru_kernel, dim3(BATCH / MR), dim3(NTH), 0, stream,
                       inputs, r_w, r_b, z_w, z_b,
                       h_w0, h_b0, h_w1, h_b1, h_w2, h_b2,
                       out, hid);
}

// Round 6
// 2708.780 us; speedup vs baseline: 1.4044x; 1.4044x over previous
//
#include <hip/hip_runtime.h>
#include <math.h>

typedef _Float16 f16;
typedef _Float16 f16x8 __attribute__((ext_vector_type(8)));
typedef float    f32x4 __attribute__((ext_vector_type(4)));

#define BATCH 256
#define SEQ   1024
#define DI    128
#define DH    128
#define DM    144
#define NTH   512
#define MR    16
#define SXS   136   // f16 stride, 128-col activation panels
#define SYS   168   // f16 stride, 160-col (144+pad) panels
#define SZS   132   // f32 stride

#define MFMA16(a, b, c) __builtin_amdgcn_mfma_f32_16x16x32_f16((a), (b), (c), 0, 0, 0)

__device__ __forceinline__ float sigm(float x) { return 1.f / (1.f + __expf(-x)); }
__device__ __forceinline__ float tanh_fast(float x) {
    const float e = __expf(2.f * x);
    return 1.f - 2.f / (e + 1.f);
}
// LDS-only barrier: global loads/stores stay in flight (T4).
__device__ __forceinline__ void bar_lds() {
    asm volatile("s_waitcnt lgkmcnt(0)" ::: "memory");
    __builtin_amdgcn_s_barrier();
}

__global__ __launch_bounds__(NTH, 2) __attribute__((amdgpu_waves_per_eu(2, 2)))
void hgru_kernel(
    const float* __restrict__ inputs,
    const float* __restrict__ r_w, const float* __restrict__ r_b,
    const float* __restrict__ z_w, const float* __restrict__ z_b,
    const float* __restrict__ h_w0, const float* __restrict__ h_b0,
    const float* __restrict__ h_w1, const float* __restrict__ h_b1,
    const float* __restrict__ h_w2, const float* __restrict__ h_b2,
    float* __restrict__ out, float* __restrict__ hid_out)
{
    __shared__ __align__(16) f16   sx [MR * SXS];   // x_{t+1} staging
    __shared__ __align__(16) f16   sh16[MR * SXS];  // h as f16 A-panel
    __shared__ __align__(16) f16   srh[MR * SXS];   // r*h A-panel
    __shared__ __align__(16) f16   sy0[MR * SYS];   // mlp act1 (zero-padded to 160)
    __shared__ __align__(16) f16   sy1[MR * SYS];   // mlp act2
    __shared__ __align__(16) float sz [MR * SZS];   // z gate f32
    __shared__ __align__(16) float shf[MR * SZS];   // master h state f32

    const int tid  = threadIdx.x;
    const int w    = tid >> 6;      // wave 0..7
    const int lane = tid & 63;
    const int ln   = lane & 15;     // A-row / B-col / C-col
    const int kg   = lane >> 4;     // k-group; C-row base = 4*kg
    const int b0   = blockIdx.x * MR;

    // wave->tile ownership (dedup so weights fit in 256 VGPR):
    // s1: gate tiles {2w, 2w+1} of 16 (w<4: r, w>=4: z)
    // s2: tile w of 9; wave 0 also tile 8
    // s3: tile w of 9; wave 1 also tile 8
    // s4: tile w of 8
    const int cnt2 = (w == 0) ? 2 : 1;
    const int cnt3 = (w == 1) ? 2 : 1;

    // ---------------- zero-init LDS ----------------
    for (int i = tid; i < MR * SYS; i += NTH) { sy0[i] = (f16)0.f; sy1[i] = (f16)0.f; }
    for (int i = tid; i < MR * SXS; i += NTH) { sh16[i] = (f16)0.f; }
    for (int i = tid; i < MR * SZS; i += NTH) { shf[i] = 0.f; }

    // ---------------- register weight fragments ----------------
    // B-frag convention (verified r3-r5): elem j = W[kt*32 + kg*8 + j][col]
    const bool is_r = (w < 4);
    const float* __restrict__ Wg = is_r ? r_w : z_w;

    f16x8 wgx[2][4], wgh[2][4];   // gates: 2 N-tiles/wave (16 frags, 64 VGPR)
    #pragma unroll
    for (int i = 0; i < 2; ++i) {
        const int col = (((2 * w + i) & 7) * 16) + ln;   // gate-local column
        #pragma unroll
        for (int kt = 0; kt < 4; ++kt) {
            f16x8 fx, fh;
            #pragma unroll
            for (int j = 0; j < 8; ++j) {
                const int k = kt * 32 + kg * 8 + j;
                fx[j] = (f16)Wg[(size_t)k * DH + col];
                fh[j] = (f16)Wg[(size_t)(DI + k) * DH + col];
            }
            wgx[i][kt] = fx; wgh[i][kt] = fh;
        }
    }

    f16x8 w0x[2][4], w0h[2][4];   // h_w0 (x-rows / rh-rows)
    #pragma unroll
    for (int i = 0; i < 2; ++i) if (i < cnt2) {
        const int col = (i ? 8 : w) * 16 + ln;
        #pragma unroll
        for (int kt = 0; kt < 4; ++kt) {
            f16x8 fx, fh;
            #pragma unroll
            for (int j = 0; j < 8; ++j) {
                const int k = kt * 32 + kg * 8 + j;
                fx[j] = (f16)h_w0[(size_t)k * DM + col];
                fh[j] = (f16)h_w0[(size_t)(DI + k) * DM + col];
            }
            w0x[i][kt] = fx; w0h[i][kt] = fh;
        }
    }

    f16x8 w1f[2][5];              // h_w1, K padded 144->160
    #pragma unroll
    for (int i = 0; i < 2; ++i) if (i < cnt3) {
        const int col = (i ? 8 : w) * 16 + ln;
        #pragma unroll
        for (int kt = 0; kt < 5; ++kt) {
            f16x8 f;
            #pragma unroll
            for (int j = 0; j < 8; ++j) {
                const int k = kt * 32 + kg * 8 + j;
                f[j] = (k < DM) ? (f16)h_w1[(size_t)k * DM + col] : (f16)0.f;
            }
            w1f[i][kt] = f;
        }
    }

    f16x8 w2f[5];                 // h_w2, tile w
    {
        const int col = w * 16 + ln;
        #pragma unroll
        for (int kt = 0; kt < 5; ++kt) {
            f16x8 f;
            #pragma unroll
            for (int j = 0; j < 8; ++j) {
                const int k = kt * 32 + kg * 8 + j;
                f[j] = (k < DM) ? (f16)h_w2[(size_t)k * DH + col] : (f16)0.f;
            }
            w2f[kt] = f;
        }
    }

    // biases
    float b1[2], b2[2], b3[2], b4;
    #pragma unroll
    for (int i = 0; i < 2; ++i)
        b1[i] = (is_r ? r_b : z_b)[(((2 * w + i) & 7) * 16) + ln];
    b2[0] = b2[1] = b3[0] = b3[1] = 0.f;
    #pragma unroll
    for (int i = 0; i < 2; ++i) if (i < cnt2) b2[i] = h_b0[(i ? 8 : w) * 16 + ln];
    #pragma unroll
    for (int i = 0; i < 2; ++i) if (i < cnt3) b3[i] = h_b1[(i ? 8 : w) * 16 + ln];
    b4 = h_b2[w * 16 + ln];

    // ---------------- x staging: waves 0-3 only ----------------
    const bool xldr = (tid < 256);
    const int  xrow = tid >> 4;
    const int  xseg = tid & 15;
    const float* __restrict__ xbase = inputs + (size_t)(b0 + (xrow & 15)) * SEQ * DI + xseg * 8;

    float4 xpA0 = {0,0,0,0}, xpA1 = {0,0,0,0};
    if (xldr) {   // publish x(0); prefetch x(1)
        const float4 a = ((const float4*)xbase)[0];
        const float4 b = ((const float4*)(xbase + 4))[0];
        f16x8 v; v[0]=(f16)a.x; v[1]=(f16)a.y; v[2]=(f16)a.z; v[3]=(f16)a.w;
                 v[4]=(f16)b.x; v[5]=(f16)b.y; v[6]=(f16)b.z; v[7]=(f16)b.w;
        *(f16x8*)(sx + xrow * SXS + xseg * 8) = v;
        xpA0 = ((const float4*)(xbase + (size_t)1 * DI))[0];
        xpA1 = ((const float4*)(xbase + (size_t)1 * DI + 4))[0];
    }
    bar_lds();

    const f32x4 z4 = {0.f, 0.f, 0.f, 0.f};
    f32x4 PG[2], PM[2];

    // ---- init PG/PM with x(0) contributions ----
    {
        f16x8 xa[4];
        #pragma unroll
        for (int kt = 0; kt < 4; ++kt)
            xa[kt] = *(const f16x8*)(sx + ln * SXS + kt * 32 + kg * 8);
        #pragma unroll
        for (int i = 0; i < 2; ++i) {
            f32x4 a = z4;
            #pragma unroll
            for (int kt = 0; kt < 4; ++kt) a = MFMA16(xa[kt], wgx[i][kt], a);
            PG[i] = a;
        }
        PM[0] = z4; PM[1] = z4;
        #pragma unroll
        for (int i = 0; i < 2; ++i) if (i < cnt2) {
            f32x4 a = z4;
            #pragma unroll
            for (int kt = 0; kt < 4; ++kt) a = MFMA16(xa[kt], w0x[i][kt], a);
            PM[i] = a;
        }
    }

    for (int t = 0; t < SEQ; ++t) {
        // prefetch x(t+2): stays in flight across lgkm-only barriers
        float4 xpB0, xpB1;
        if (xldr) {
            const int tn = (t + 2 < SEQ) ? t + 2 : SEQ - 1;
            xpB0 = ((const float4*)(xbase + (size_t)tn * DI))[0];
            xpB1 = ((const float4*)(xbase + (size_t)tn * DI + 4))[0];
        }

        // ======== stage 1: gates — h-part into PG ========
        {
            f16x8 ha[4];
            #pragma unroll
            for (int kt = 0; kt < 4; ++kt)
                ha[kt] = *(const f16x8*)(sh16 + ln * SXS + kt * 32 + kg * 8);
            #pragma unroll
            for (int i = 0; i < 2; ++i) {
                f32x4 a = PG[i];
                #pragma unroll
                for (int kt = 0; kt < 4; ++kt) a = MFMA16(ha[kt], wgh[i][kt], a);
                PG[i] = a;
            }
        }
        #pragma unroll
        for (int i = 0; i < 2; ++i) {
            const int n = (((2 * w + i) & 7) * 16) + ln;
            #pragma unroll
            for (int j = 0; j < 4; ++j) {
                const int m = 4 * kg + j;
                const float g = sigm(PG[i][j] + b1[i]);
                if (is_r) srh[m * SXS + n] = (f16)(g * shf[m * SZS + n]);
                else      sz[m * SZS + n] = g;
            }
        }
        bar_lds(); // A

        // ======== stage 2: y0 = relu(PM + rh @ w0h + b) ========
        {
            f16x8 ra[4];
            #pragma unroll
            for (int kt = 0; kt < 4; ++kt)
                ra[kt] = *(const f16x8*)(srh + ln * SXS + kt * 32 + kg * 8);
            #pragma unroll
            for (int i = 0; i < 2; ++i) if (i < cnt2) {
                f32x4 a = PM[i];
                #pragma unroll
                for (int kt = 0; kt < 4; ++kt) a = MFMA16(ra[kt], w0h[i][kt], a);
                const int n = (i ? 8 : w) * 16 + ln;
                #pragma unroll
                for (int j = 0; j < 4; ++j)
                    sy0[(4 * kg + j) * SYS + n] = (f16)fmaxf(a[j] + b2[i], 0.f);
            }
        }
        // publish x(t+1)
        if (xldr) {
            f16x8 v; v[0]=(f16)xpA0.x; v[1]=(f16)xpA0.y; v[2]=(f16)xpA0.z; v[3]=(f16)xpA0.w;
                     v[4]=(f16)xpA1.x; v[5]=(f16)xpA1.y; v[6]=(f16)xpA1.z; v[7]=(f16)xpA1.w;
            *(f16x8*)(sx + xrow * SXS + xseg * 8) = v;
        }
        bar_lds(); // B

        // ======== stage 3: y1 = relu(y0 @ h_w1 + b) ========
        {
            f16x8 ya[5];
            #pragma unroll
            for (int kt = 0; kt < 5; ++kt)
                ya[kt] = *(const f16x8*)(sy0 + ln * SYS + kt * 32 + kg * 8);
            #pragma unroll
            for (int i = 0; i < 2; ++i) if (i < cnt3) {
                f32x4 a = z4;
                #pragma unroll
                for (int kt = 0; kt < 5; ++kt) a = MFMA16(ya[kt], w1f[i][kt], a);
                const int n = (i ? 8 : w) * 16 + ln;
                #pragma unroll
                for (int j = 0; j < 4; ++j)
                    sy1[(4 * kg + j) * SYS + n] = (f16)fmaxf(a[j] + b3[i], 0.f);
            }
        }
        bar_lds(); // C

        // ======== stage 4: h~ = tanh(y1 @ h_w2 + b2); h update ========
        f32x4 r4;
        {
            f16x8 za[5];
            #pragma unroll
            for (int kt = 0; kt < 5; ++kt)
                za[kt] = *(const f16x8*)(sy1 + ln * SYS + kt * 32 + kg * 8);
            f32x4 a = z4;
            #pragma unroll
            for (int kt = 0; kt < 5; ++kt) a = MFMA16(za[kt], w2f[kt], a);
            r4 = a;
        }
        // shadow: next step's x-projections (off critical path)
        {
            f16x8 xa[4];
            #pragma unroll
            for (int kt = 0; kt < 4; ++kt)
                xa[kt] = *(const f16x8*)(sx + ln * SXS + kt * 32 + kg * 8);
            #pragma unroll
            for (int i = 0; i < 2; ++i) {
                f32x4 a = z4;
                #pragma unroll
                for (int kt = 0; kt < 4; ++kt) a = MFMA16(xa[kt], wgx[i][kt], a);
                PG[i] = a;
            }
            #pragma unroll
            for (int i = 0; i < 2; ++i) if (i < cnt2) {
                f32x4 a = z4;
                #pragma unroll
                for (int kt = 0; kt < 4; ++kt) a = MFMA16(xa[kt], w0x[i][kt], a);
                PM[i] = a;
            }
        }
        {
            const int n4 = w * 16 + ln;
            #pragma unroll
            for (int j = 0; j < 4; ++j) {
                const int m = 4 * kg + j;
                const float ht = tanh_fast(r4[j] + b4);
                const float zz = sz[m * SZS + n4];
                const float hn = (1.f - zz) * shf[m * SZS + n4] + zz * ht;
                shf[m * SZS + n4] = hn;
                sh16[m * SXS + n4] = (f16)hn;
                out[((size_t)(b0 + m) * SEQ + t) * DH + n4] = hn;  // floats in VMEM queue
            }
        }
        bar_lds(); // D

        xpA0 = xpB0; xpA1 = xpB1;
    }

    for (int i = tid; i < MR * DH; i += NTH)
        hid_out[(size_t)(b0 + (i >> 7)) * DH + (i & 127)] = shf[(i >> 7) * SZS + (i & 127)];
}

extern "C" void kernel_launch(void* const* d_in, const int* in_sizes, int n_in,
                              void* d_out, int out_size, void* d_ws, size_t ws_size,
                              hipStream_t stream) {
    const float* inputs = (const float*)d_in[0];
    const float* r_w  = (const float*)d_in[1];
    const float* r_b  = (const float*)d_in[2];
    const float* z_w  = (const float*)d_in[3];
    const float* z_b  = (const float*)d_in[4];
    const float* h_w0 = (const float*)d_in[5];
    const float* h_b0 = (const float*)d_in[6];
    const float* h_w1 = (const float*)d_in[7];
    const float* h_b1 = (const float*)d_in[8];
    const float* h_w2 = (const float*)d_in[9];
    const float* h_b2 = (const float*)d_in[10];

    float* out = (float*)d_out;
    float* hid = out + (size_t)BATCH * SEQ * DH;

    hipLaunchKernelGGL(hgru_kernel, dim3(BATCH / MR), dim3(NTH), 0, stream,
                       inputs, r_w, r_b, z_w, z_b,
                       h_w0, h_b0, h_w1, h_b1, h_w2, h_b2,
                       out, hid);
}